// Round 9
// baseline (1396.916 us; speedup 1.0000x reference)
//
#include <hip/hip_runtime.h>
#include <hip/hip_cooperative_groups.h>
#include <cstdint>
#include <cstddef>

namespace cg = cooperative_groups;

// GNNEncoder: 2x (edge-MLP GNN layer) + mean pool + MLP head. bf16 node pipeline.
// R9: single cooperative mega-kernel (11 grid.sync phases) to kill ~90us of
// dispatch-boundary overhead. Fallback to discrete launches if coop launch fails.

static constexpr int GRAPHS = 64;

using bf16x8 = __attribute__((ext_vector_type(8))) short;
using f32x4 = __attribute__((ext_vector_type(4))) float;

__device__ inline float bf2f(uint u) { return __builtin_bit_cast(float, u << 16); }
__device__ inline float bf2f_hi(uint u) { return __builtin_bit_cast(float, u & 0xffff0000u); }
__device__ inline ushort f2bf(float f) {
    uint u = __builtin_bit_cast(uint, f);
    return (ushort)((u + 0x7fffu + ((u >> 16) & 1u)) >> 16);
}
__device__ inline int gmin(int a, int b) { return a < b ? a : b; }

union SM {
    uint4 xt[64 * 17];               // 17408 B node tile (padded stride 17)
    int ts[256];                     // scan scratch
    struct { float p[128]; float h[128]; } hd;
};

// ---------------- shared device bodies ----------------
template <bool F32IN>
__device__ __forceinline__ void stage_tile(SM& sm, const void* Xin, int node0) {
    int t = threadIdx.x;
    int row = t >> 2;
#pragma unroll
    for (int i = 0; i < 4; ++i) {
        int chunk = (t & 3) + i * 4;
        uint4 v;
        if constexpr (F32IN) {
            const float* s = (const float*)Xin + (size_t)(node0 + row) * 128 + chunk * 8;
            float4 v0 = *reinterpret_cast<const float4*>(s);
            float4 v1 = *reinterpret_cast<const float4*>(s + 4);
            uint* vu = reinterpret_cast<uint*>(&v);
            vu[0] = (uint)f2bf(v0.x) | ((uint)f2bf(v0.y) << 16);
            vu[1] = (uint)f2bf(v0.z) | ((uint)f2bf(v0.w) << 16);
            vu[2] = (uint)f2bf(v1.x) | ((uint)f2bf(v1.y) << 16);
            vu[3] = (uint)f2bf(v1.z) | ((uint)f2bf(v1.w) << 16);
        } else {
            v = *reinterpret_cast<const uint4*>((const ushort*)Xin + (size_t)(node0 + row) * 128 + chunk * 8);
        }
        sm.xt[row * 17 + chunk] = v;
    }
}

template <int NOUT, bool RELU, bool DEGBIAS>
__device__ __forceinline__ void ngemm_compute(SM& sm, const ushort* Wt, const float* bias,
                                              const int* rp, ushort* Y, int node0) {
    int t = threadIdx.x;
    int lane = t & 63, wv = t >> 6;
    int lr = lane & 15, lg = lane >> 4;

    bf16x8 bfr[4][4];
#pragma unroll
    for (int rs = 0; rs < 4; ++rs)
#pragma unroll
        for (int kk = 0; kk < 4; ++kk)
            bfr[rs][kk] = *reinterpret_cast<const bf16x8*>(&sm.xt[(rs * 16 + lr) * 17 + lg + 4 * kk]);

    float degf[4];
    if constexpr (DEGBIAS) {
#pragma unroll
        for (int rs = 0; rs < 4; ++rs) {
            int r_ = node0 + rs * 16 + lr;
            degf[rs] = (float)(rp[r_ + 1] - rp[r_]);
        }
    }

    constexpr int NBW = NOUT / 64;
#pragma unroll
    for (int q = 0; q < NBW; ++q) {
        int nb = wv * NBW + q;
        const ushort* wrow = Wt + (size_t)(nb * 16 + lr) * 128 + lg * 8;
        bf16x8 af[4];
#pragma unroll
        for (int kk = 0; kk < 4; ++kk) af[kk] = *reinterpret_cast<const bf16x8*>(wrow + kk * 32);
        float4 bb = *reinterpret_cast<const float4*>(bias + nb * 16 + lg * 4);
        const float* bbp = reinterpret_cast<const float*>(&bb);
#pragma unroll
        for (int rs = 0; rs < 4; ++rs) {
            f32x4 acc = {0.f, 0.f, 0.f, 0.f};
#pragma unroll
            for (int kk = 0; kk < 4; ++kk)
                acc = __builtin_amdgcn_mfma_f32_16x16x32_bf16(af[kk], bfr[rs][kk], acc, 0, 0, 0);
            ushort4 o;
#pragma unroll
            for (int r = 0; r < 4; ++r) {
                float v = acc[r] + (DEGBIAS ? degf[rs] * bbp[r] : bbp[r]);
                if constexpr (RELU) v = fmaxf(v, 0.f);
                reinterpret_cast<ushort*>(&o)[r] = f2bf(v);
            }
            *reinterpret_cast<ushort4*>(Y + (size_t)(node0 + rs * 16 + lr) * NOUT + nb * 16 + lg * 4) = o;
        }
    }
}

template <int NOUT, bool RELU, bool DEGBIAS, bool F32IN>
__device__ __forceinline__ void ngemm_tile(SM& sm, const void* Xin, const ushort* Wt,
                                           const float* bias, const int* rp, ushort* Y, int node0) {
    stage_tile<F32IN>(sm, Xin, node0);
    __syncthreads();
    ngemm_compute<NOUT, RELU, DEGBIAS>(sm, Wt, bias, rp, Y, node0);
    __syncthreads();
}

// fused: H1 = relu(Hagg@W2t^T + deg*b2) kept in regs -> LDS -> AB2 = H1@W1n^T + bn
__device__ __forceinline__ void layer_tile(SM& sm, const ushort* Hagg,
                                           const ushort* W2t, const float* b2,
                                           const ushort* W1n, const float* bn,
                                           const int* rp, ushort* AB2, int node0) {
    stage_tile<false>(sm, Hagg, node0);
    __syncthreads();
    int t = threadIdx.x;
    int lane = t & 63, wv = t >> 6;
    int lr = lane & 15, lg = lane >> 4;

    bf16x8 bfr[4][4];
#pragma unroll
    for (int rs = 0; rs < 4; ++rs)
#pragma unroll
        for (int kk = 0; kk < 4; ++kk)
            bfr[rs][kk] = *reinterpret_cast<const bf16x8*>(&sm.xt[(rs * 16 + lr) * 17 + lg + 4 * kk]);

    float degf[4];
#pragma unroll
    for (int rs = 0; rs < 4; ++rs) {
        int r_ = node0 + rs * 16 + lr;
        degf[rs] = (float)(rp[r_ + 1] - rp[r_]);
    }

    ushort4 h1o[2][4];
#pragma unroll
    for (int q = 0; q < 2; ++q) {
        int nb = wv * 2 + q;
        const ushort* wrow = W2t + (size_t)(nb * 16 + lr) * 128 + lg * 8;
        bf16x8 af[4];
#pragma unroll
        for (int kk = 0; kk < 4; ++kk) af[kk] = *reinterpret_cast<const bf16x8*>(wrow + kk * 32);
        float4 bb = *reinterpret_cast<const float4*>(b2 + nb * 16 + lg * 4);
        const float* bbp = reinterpret_cast<const float*>(&bb);
#pragma unroll
        for (int rs = 0; rs < 4; ++rs) {
            f32x4 acc = {0.f, 0.f, 0.f, 0.f};
#pragma unroll
            for (int kk = 0; kk < 4; ++kk)
                acc = __builtin_amdgcn_mfma_f32_16x16x32_bf16(af[kk], bfr[rs][kk], acc, 0, 0, 0);
#pragma unroll
            for (int r = 0; r < 4; ++r) {
                float v = fmaxf(acc[r] + degf[rs] * bbp[r], 0.f);
                reinterpret_cast<ushort*>(&h1o[q][rs])[r] = f2bf(v);
            }
        }
    }
    __syncthreads();
    char* xb = reinterpret_cast<char*>(sm.xt);
#pragma unroll
    for (int q = 0; q < 2; ++q)
#pragma unroll
        for (int rs = 0; rs < 4; ++rs) {
            int row = rs * 16 + lr;
            int colc = (wv * 2 + q) * 16 + lg * 4;
            *reinterpret_cast<ushort4*>(xb + row * 272 + (colc >> 3) * 16 + (colc & 7) * 2) = h1o[q][rs];
        }
    __syncthreads();
    ngemm_compute<256, false, false>(sm, W1n, bn, nullptr, AB2, node0);
    __syncthreads();
}

__device__ __forceinline__ void accum8(uint4 b, const float2* a, float2* acc) {
    const uint* bu = reinterpret_cast<const uint*>(&b);
#pragma unroll
    for (int j = 0; j < 4; ++j) {
        uint u = bu[j];
        acc[j].x += fmaxf(a[j].x + bf2f(u), 0.f);
        acc[j].y += fmaxf(a[j].y + bf2f_hi(u), 0.f);
    }
}

__device__ __forceinline__ void agg_node(const ushort* AB, const int* rp, const int* col,
                                         ushort* Hagg, int n, int lane) {
    int fs = lane & 15;
    int lg = lane >> 4;
    uint4 av = *reinterpret_cast<const uint4*>(AB + (size_t)n * 256 + fs * 8);
    float2 a[4];
    {
        const uint* au = reinterpret_cast<const uint*>(&av);
#pragma unroll
        for (int j = 0; j < 4; ++j) a[j] = make_float2(bf2f(au[j]), bf2f_hi(au[j]));
    }
    float2 acc[4] = {{0.f, 0.f}, {0.f, 0.f}, {0.f, 0.f}, {0.f, 0.f}};
    int e0 = rp[n], e1 = rp[n + 1];
    int eMain = e0 + ((e1 - e0) & ~7);
    for (int eb = e0; eb < eMain; eb += 8) {
        int sA = col[eb + lg];
        int sB = col[eb + lg + 4];
        uint4 bA = *reinterpret_cast<const uint4*>(AB + (size_t)sA * 256 + 128 + fs * 8);
        uint4 bB = *reinterpret_cast<const uint4*>(AB + (size_t)sB * 256 + 128 + fs * 8);
        accum8(bA, a, acc);
        accum8(bB, a, acc);
    }
    for (int e = eMain + lg; e < e1; e += 4) {
        int s = col[e];
        uint4 b = *reinterpret_cast<const uint4*>(AB + (size_t)s * 256 + 128 + fs * 8);
        accum8(b, a, acc);
    }
#pragma unroll
    for (int j = 0; j < 4; ++j) {
        acc[j].x += __shfl_xor(acc[j].x, 16);
        acc[j].y += __shfl_xor(acc[j].y, 16);
        acc[j].x += __shfl_xor(acc[j].x, 32);
        acc[j].y += __shfl_xor(acc[j].y, 32);
    }
    if (lg == 0) {
        uint4 o;
        uint* ou = reinterpret_cast<uint*>(&o);
#pragma unroll
        for (int j = 0; j < 4; ++j)
            ou[j] = (uint)f2bf(acc[j].x) | ((uint)f2bf(acc[j].y) << 16);
        *reinterpret_cast<uint4*>(Hagg + (size_t)n * 128 + fs * 8) = o;
    }
}

__device__ __forceinline__ void head_body(SM& sm, const float* psum, const int* gs,
                                          const float* wm1, const float* bm1,
                                          const float* wm2, const float* bm2,
                                          float* out, int g, int t) {
    int cnt = gs[g + 1] - gs[g];
    float rcp = 1.0f / (float)(cnt > 0 ? cnt : 1);
    if (t < 128) sm.hd.p[t] = psum[g * 128 + t] * rcp;
    __syncthreads();
    if (t < 128) {
        float a = bm1[t];
        for (int k = 0; k < 128; ++k) a += sm.hd.p[k] * wm1[k * 128 + t];
        sm.hd.h[t] = fmaxf(a, 0.f);
    }
    __syncthreads();
    if (t < 128) {
        float acc[4];
#pragma unroll
        for (int j = 0; j < 4; ++j) acc[j] = bm2[j * 128 + t];
        for (int k = 0; k < 128; ++k) {
            float hv = sm.hd.h[k];
#pragma unroll
            for (int j = 0; j < 4; ++j) acc[j] += hv * wm2[k * 512 + j * 128 + t];
        }
#pragma unroll
        for (int j = 0; j < 4; ++j) out[(size_t)g * 512 + j * 128 + t] = acc[j];
    }
}

// ---------------- cooperative mega-kernel ----------------
struct Params {
    const float* x; const int* srcp; const int* dstp; const int* batch;
    const float *w1_1, *b1_1, *w1_2, *b1_2, *w2_1, *b2_1, *w2_2, *b2_2, *wm1, *bm1, *wm2, *bm2;
    float* out;
    ushort *AB1, *AB2, *Hagg, *H;
    int *rp, *cursor, *col, *gs, *bpart;
    float* psum;
    ushort *wt1a, *wt1b, *wt2a, *wt2b;
    float *b256_1, *b256_2;
    int M, E;
};

__global__ __launch_bounds__(256, 4) void mega_k(Params p) {
    cg::grid_group grid = cg::this_grid();
    __shared__ SM sm;
    const int t = threadIdx.x;
    const int b = blockIdx.x;
    const int NBk = gridDim.x;
    const int gtid = b * 256 + t;
    const int gsz = NBk * 256;
    const int M = p.M, E = p.E;
    const int NT = M / 64;

    // ---- P0: weights cast/transpose, biases, deg=0, psum=0, gstart ----
    for (int i = gtid; i < 32768; i += gsz) {
        int j = i >> 7, k = i & 127;
        p.wt1a[i] = f2bf((j < 128) ? p.w1_1[k * 128 + j] : p.w1_1[(128 + k) * 128 + (j - 128)]);
        p.wt1b[i] = f2bf((j < 128) ? p.w2_1[k * 128 + j] : p.w2_1[(128 + k) * 128 + (j - 128)]);
    }
    for (int i = gtid; i < 16384; i += gsz) {
        int j = i >> 7, k = i & 127;
        p.wt2a[i] = f2bf(p.w1_2[k * 128 + j]);
        p.wt2b[i] = f2bf(p.w2_2[k * 128 + j]);
    }
    for (int i = gtid; i < 256; i += gsz) {
        p.b256_1[i] = (i < 128) ? p.b1_1[i] : 0.f;
        p.b256_2[i] = (i < 128) ? p.b2_1[i] : 0.f;
    }
    for (int i = gtid; i < M; i += gsz) p.cursor[i] = 0;
    for (int i = gtid; i < GRAPHS * 128; i += gsz) p.psum[i] = 0.f;
    if (gtid <= GRAPHS) {
        int lo = 0, hi = M;
        while (lo < hi) {
            int mid = (lo + hi) >> 1;
            if (p.batch[mid] < gtid) lo = mid + 1;
            else hi = mid;
        }
        p.gs[gtid] = lo;
    }
    __threadfence(); grid.sync();

    // ---- P1: hist (deg) + layer1 edge-GEMM (independent) ----
    for (int i = gtid; i < E; i += gsz) atomicAdd(&p.cursor[p.dstp[i]], 1);
    for (int tile = b; tile < NT; tile += NBk)
        ngemm_tile<256, false, false, true>(sm, p.x, p.wt1a, p.b256_1, p.rp, p.AB1, tile * 64);
    __threadfence(); grid.sync();

    // ---- P2: 2-level exclusive scan of deg -> rp, cursor ----
    const int CH = (M + gsz - 1) / gsz;
    const int i0 = gtid * CH, i1 = gmin(M, i0 + CH);
    int s = 0;
    for (int i = i0; i < i1; ++i) s += p.cursor[i];
    sm.ts[t] = s;
    __syncthreads();
    for (int off = 1; off < 256; off <<= 1) {
        int v = (t >= off) ? sm.ts[t - off] : 0;
        __syncthreads();
        sm.ts[t] += v;
        __syncthreads();
    }
    int texcl = sm.ts[t] - s;
    if (t == 255) p.bpart[b] = sm.ts[255];
    __threadfence(); grid.sync();
    if (b == 0) {
        int K = (NBk + 255) / 256;
        int a0 = t * K, a1 = gmin(NBk, a0 + K);
        int ls = 0;
        for (int u = a0; u < a1; ++u) ls += p.bpart[u];
        sm.ts[t] = ls;
        __syncthreads();
        for (int off = 1; off < 256; off <<= 1) {
            int v = (t >= off) ? sm.ts[t - off] : 0;
            __syncthreads();
            sm.ts[t] += v;
            __syncthreads();
        }
        int run = sm.ts[t] - ls;
        for (int u = a0; u < a1; ++u) {
            int v = p.bpart[u];
            p.bpart[u] = run;
            run += v;
        }
        if (t == 255) p.rp[M] = sm.ts[255];
    }
    __threadfence(); grid.sync();
    {
        int off = p.bpart[b] + texcl;
        for (int i = i0; i < i1; ++i) {
            int d = p.cursor[i];
            p.rp[i] = off;
            p.cursor[i] = off;
            off += d;
        }
    }
    __threadfence(); grid.sync();

    // ---- P3: fill CSR col ----
    for (int i = gtid; i < E; i += gsz) {
        int d = p.dstp[i];
        int pos = atomicAdd(&p.cursor[d], 1);
        p.col[pos] = p.srcp[i];
    }
    __threadfence(); grid.sync();

    // ---- P4: agg layer1 ----
    {
        int lane = t & 63, wv = t >> 6;
        for (int n = b * 4 + wv; n < M; n += NBk * 4) agg_node(p.AB1, p.rp, p.col, p.Hagg, n, lane);
    }
    __threadfence(); grid.sync();

    // ---- P5: fused H1-GEMM + layer2 edge-GEMM ----
    for (int tile = b; tile < NT; tile += NBk)
        layer_tile(sm, p.Hagg, p.wt2a, p.b1_2, p.wt1b, p.b256_2, p.rp, p.AB2, tile * 64);
    __threadfence(); grid.sync();

    // ---- P6: agg layer2 ----
    {
        int lane = t & 63, wv = t >> 6;
        for (int n = b * 4 + wv; n < M; n += NBk * 4) agg_node(p.AB2, p.rp, p.col, p.Hagg, n, lane);
    }
    __threadfence(); grid.sync();

    // ---- P7: H2-GEMM ----
    for (int tile = b; tile < NT; tile += NBk)
        ngemm_tile<128, true, true, false>(sm, p.Hagg, p.wt2b, p.b2_2, p.rp, p.H, tile * 64);
    __threadfence(); grid.sync();

    // ---- P8: mean-pool partial sums ----
    {
        int NC = NBk * 2;
        int step = (M + NC - 1) / NC;
        int c = b * 2 + (t >> 7);
        int f = t & 127;
        int n0 = c * step, n1 = gmin(M, n0 + step);
        if (n0 < n1) {
            int g = p.batch[n0];
            float acc = 0.f;
            for (int n = n0; n < n1; ++n) {
                int bg = p.batch[n];
                if (bg != g) {
                    atomicAdd(&p.psum[g * 128 + f], acc);
                    acc = 0.f;
                    g = bg;
                }
                acc += bf2f((uint)p.H[(size_t)n * 128 + f]);
            }
            atomicAdd(&p.psum[g * 128 + f], acc);
        }
    }
    __threadfence(); grid.sync();

    // ---- P9: head MLP (blocks 0..63) ----
    if (b < GRAPHS)
        head_body(sm, p.psum, p.gs, p.wm1, p.bm1, p.wm2, p.bm2, p.out, b, t);
}

// ---------------- fallback discrete kernels ----------------
__global__ __launch_bounds__(256) void setup_k(
    const float* __restrict__ w1_1, const float* __restrict__ w2_1,
    const float* __restrict__ w1_2, const float* __restrict__ w2_2,
    const float* __restrict__ b1_1, const float* __restrict__ b2_1,
    ushort* __restrict__ wt1a, ushort* __restrict__ wt1b,
    ushort* __restrict__ wt2a, ushort* __restrict__ wt2b,
    float* __restrict__ b256_1, float* __restrict__ b256_2,
    int* __restrict__ deg, float* __restrict__ psum,
    const int* __restrict__ batch, int* __restrict__ gs, int M, int nbDeg) {
    int b = blockIdx.x, t = threadIdx.x;
    if (b < 128) {
        int i = b * 256 + t;
        int j = i >> 7, k = i & 127;
        wt1a[i] = f2bf((j < 128) ? w1_1[k * 128 + j] : w1_1[(128 + k) * 128 + (j - 128)]);
        wt1b[i] = f2bf((j < 128) ? w2_1[k * 128 + j] : w2_1[(128 + k) * 128 + (j - 128)]);
        return;
    }
    b -= 128;
    if (b < 64) {
        int i = b * 256 + t;
        int j = i >> 7, k = i & 127;
        wt2a[i] = f2bf(w1_2[k * 128 + j]);
        wt2b[i] = f2bf(w2_2[k * 128 + j]);
        return;
    }
    b -= 64;
    if (b < nbDeg) {
        int i = b * 256 + t;
        if (i < M) deg[i] = 0;
        return;
    }
    b -= nbDeg;
    if (b < 32) {
        psum[b * 256 + t] = 0.f;
        return;
    }
    b -= 32;
    if (b == 0) {
        b256_1[t] = (t < 128) ? b1_1[t] : 0.f;
        b256_2[t] = (t < 128) ? b2_1[t] : 0.f;
        return;
    }
    if (t > GRAPHS) return;
    int lo = 0, hi = M;
    while (lo < hi) {
        int mid = (lo + hi) >> 1;
        if (batch[mid] < t) lo = mid + 1;
        else hi = mid;
    }
    gs[t] = lo;
}

__global__ __launch_bounds__(256) void hist_k(const int* __restrict__ dst, int* __restrict__ deg, int E) {
    int i = blockIdx.x * 256 + threadIdx.x;
    if (i < E) atomicAdd(&deg[dst[i]], 1);
}

__global__ __launch_bounds__(256) void scan_k(const int* __restrict__ deg, int* __restrict__ rp,
                                              int* __restrict__ cursor, int M) {
    __shared__ int ts[256];
    int t = threadIdx.x;
    int per = (M + 255) / 256;
    per = (per + 3) & ~3;
    int s0 = t * per;
    int s1 = s0 + per; if (s1 > M) s1 = M;
    int sum = 0;
    for (int i = s0; i < s1; i += 4) {
        int4 v = *reinterpret_cast<const int4*>(deg + i);
        sum += v.x + v.y + v.z + v.w;
    }
    ts[t] = sum;
    __syncthreads();
    for (int off = 1; off < 256; off <<= 1) {
        int v = (t >= off) ? ts[t - off] : 0;
        __syncthreads();
        ts[t] += v;
        __syncthreads();
    }
    int run = ts[t] - sum;
    for (int i = s0; i < s1; i += 4) {
        int4 v = *reinterpret_cast<const int4*>(deg + i);
        int4 o;
        o.x = run; run += v.x;
        o.y = run; run += v.y;
        o.z = run; run += v.z;
        o.w = run; run += v.w;
        *reinterpret_cast<int4*>(rp + i) = o;
        *reinterpret_cast<int4*>(cursor + i) = o;
    }
    if (t == 0) rp[M] = ts[255];
}

__global__ __launch_bounds__(256) void fill_k(const int* __restrict__ src, const int* __restrict__ dst,
                                              int* __restrict__ cursor, int* __restrict__ col, int E) {
    int i = blockIdx.x * 256 + threadIdx.x;
    if (i < E) {
        int d = dst[i];
        int pnum = atomicAdd(&cursor[d], 1);
        col[pnum] = src[i];
    }
}

template <int NOUT, bool RELU, bool DEGBIAS, bool F32IN>
__global__ __launch_bounds__(256) void ngemm_g(const void* __restrict__ Xin, const ushort* __restrict__ Wt,
                                               const float* __restrict__ bias, const int* __restrict__ rp,
                                               ushort* __restrict__ Y) {
    __shared__ SM sm;
    ngemm_tile<NOUT, RELU, DEGBIAS, F32IN>(sm, Xin, Wt, bias, rp, Y, blockIdx.x * 64);
}

__global__ __launch_bounds__(256) void layer_g(const ushort* __restrict__ Hagg,
                                               const ushort* __restrict__ W2t, const float* __restrict__ b2,
                                               const ushort* __restrict__ W1n, const float* __restrict__ bn,
                                               const int* __restrict__ rp, ushort* __restrict__ AB2) {
    __shared__ SM sm;
    layer_tile(sm, Hagg, W2t, b2, W1n, bn, rp, AB2, blockIdx.x * 64);
}

__global__ __launch_bounds__(256) void agg_g(const ushort* __restrict__ AB, const int* __restrict__ rp,
                                             const int* __restrict__ col, ushort* __restrict__ Hagg, int M) {
    int lane = threadIdx.x & 63, wv = threadIdx.x >> 6;
    int n = blockIdx.x * 4 + wv;
    if (n < M) agg_node(AB, rp, col, Hagg, n, lane);
}

__global__ __launch_bounds__(128) void pool_k(const ushort* __restrict__ H, const int* __restrict__ batch,
                                              float* __restrict__ psum, int M, int nblk) {
    int f = threadIdx.x;
    int chunk = (M + nblk - 1) / nblk;
    int n0 = blockIdx.x * chunk;
    int n1 = n0 + chunk;
    if (n1 > M) n1 = M;
    if (n0 >= n1) return;
    int g = batch[n0];
    float acc = 0.f;
    for (int n = n0; n < n1; ++n) {
        int bg = batch[n];
        if (bg != g) {
            atomicAdd(&psum[g * 128 + f], acc);
            acc = 0.f;
            g = bg;
        }
        acc += bf2f((uint)H[(size_t)n * 128 + f]);
    }
    atomicAdd(&psum[g * 128 + f], acc);
}

__global__ __launch_bounds__(256) void head_g(const float* __restrict__ psum, const int* __restrict__ gs,
                                              const float* __restrict__ wm1, const float* __restrict__ bm1,
                                              const float* __restrict__ wm2, const float* __restrict__ bm2,
                                              float* __restrict__ out) {
    __shared__ SM sm;
    head_body(sm, psum, gs, wm1, bm1, wm2, bm2, out, blockIdx.x, threadIdx.x);
}

extern "C" void kernel_launch(void* const* d_in, const int* in_sizes, int n_in,
                              void* d_out, int out_size, void* d_ws, size_t ws_size,
                              hipStream_t stream) {
    const float* x = (const float*)d_in[0];
    const int* ei = (const int*)d_in[1];
    const int* batch = (const int*)d_in[2];
    const float* w1_1 = (const float*)d_in[3];
    const float* b1_1 = (const float*)d_in[4];
    const float* w1_2 = (const float*)d_in[5];
    const float* b1_2 = (const float*)d_in[6];
    const float* w2_1 = (const float*)d_in[7];
    const float* b2_1 = (const float*)d_in[8];
    const float* w2_2 = (const float*)d_in[9];
    const float* b2_2 = (const float*)d_in[10];
    const float* wm1 = (const float*)d_in[11];
    const float* bm1 = (const float*)d_in[12];
    const float* wm2 = (const float*)d_in[13];
    const float* bm2 = (const float*)d_in[14];

    const int E = in_sizes[1] / 2;
    const int M = in_sizes[0] / 128;
    const int* srcp = ei;
    const int* dstp = ei + E;

    char* ws = (char*)d_ws;
    size_t off = 0;
    auto alloc = [&](size_t bytes) -> void* {
        void* ptr = ws + off;
        off += (bytes + 255) & ~(size_t)255;
        return ptr;
    };
    ushort* AB1 = (ushort*)alloc((size_t)M * 256 * 2);
    ushort* AB2 = (ushort*)alloc((size_t)M * 256 * 2);
    ushort* Hagg = (ushort*)alloc((size_t)M * 128 * 2);
    ushort* H = (ushort*)alloc((size_t)M * 128 * 2);
    int* rp = (int*)alloc((size_t)(M + 1) * 4);
    int* cursor = (int*)alloc((size_t)M * 4);
    int* col = (int*)alloc((size_t)E * 4);
    int* gs = (int*)alloc((GRAPHS + 1) * 4);
    int* bpart = (int*)alloc(4096 * 4);
    float* psum = (float*)alloc(GRAPHS * 128 * 4);
    ushort* wt1a = (ushort*)alloc(256 * 128 * 2);
    ushort* wt1b = (ushort*)alloc(256 * 128 * 2);
    ushort* wt2a = (ushort*)alloc(128 * 128 * 2);
    ushort* wt2b = (ushort*)alloc(128 * 128 * 2);
    float* b256_1 = (float*)alloc(256 * 4);
    float* b256_2 = (float*)alloc(256 * 4);

    // ---- try cooperative mega-kernel ----
    bool coop_ok = false;
    {
        int occ = 0;
        hipError_t oe = hipOccupancyMaxActiveBlocksPerMultiprocessor(&occ, (const void*)mega_k, 256, 0);
        int NB = (oe == hipSuccess && occ > 0) ? occ * 256 : 0;
        if (NB > 2048) NB = 2048;
        if (NB >= 256) {
            Params pr;
            pr.x = x; pr.srcp = srcp; pr.dstp = dstp; pr.batch = batch;
            pr.w1_1 = w1_1; pr.b1_1 = b1_1; pr.w1_2 = w1_2; pr.b1_2 = b1_2;
            pr.w2_1 = w2_1; pr.b2_1 = b2_1; pr.w2_2 = w2_2; pr.b2_2 = b2_2;
            pr.wm1 = wm1; pr.bm1 = bm1; pr.wm2 = wm2; pr.bm2 = bm2;
            pr.out = (float*)d_out;
            pr.AB1 = AB1; pr.AB2 = AB2; pr.Hagg = Hagg; pr.H = H;
            pr.rp = rp; pr.cursor = cursor; pr.col = col; pr.gs = gs; pr.bpart = bpart;
            pr.psum = psum;
            pr.wt1a = wt1a; pr.wt1b = wt1b; pr.wt2a = wt2a; pr.wt2b = wt2b;
            pr.b256_1 = b256_1; pr.b256_2 = b256_2;
            pr.M = M; pr.E = E;
            void* args[] = {&pr};
            hipError_t le = hipLaunchCooperativeKernel((const void*)mega_k, dim3(NB), dim3(256),
                                                       args, 0, stream);
            coop_ok = (le == hipSuccess);
            if (!coop_ok) (void)hipGetLastError();
        }
    }

    if (!coop_ok) {
        // ---- fallback: discrete launches (R8-equivalent) ----
        const int nbDeg = (M + 255) / 256;
        setup_k<<<128 + 64 + nbDeg + 32 + 2, 256, 0, stream>>>(
            w1_1, w2_1, w1_2, w2_2, b1_1, b2_1, wt1a, wt1b, wt2a, wt2b, b256_1, b256_2,
            cursor, psum, batch, gs, M, nbDeg);
        hist_k<<<(E + 255) / 256, 256, 0, stream>>>(dstp, cursor, E);
        scan_k<<<1, 256, 0, stream>>>(cursor, rp, cursor, M);
        fill_k<<<(E + 255) / 256, 256, 0, stream>>>(srcp, dstp, cursor, col, E);
        ngemm_g<256, false, false, true><<<M / 64, 256, 0, stream>>>(x, wt1a, b256_1, nullptr, AB1);
        agg_g<<<(M + 3) / 4, 256, 0, stream>>>(AB1, rp, col, Hagg, M);
        layer_g<<<M / 64, 256, 0, stream>>>(Hagg, wt2a, b1_2, wt1b, b256_2, rp, AB2);
        agg_g<<<(M + 3) / 4, 256, 0, stream>>>(AB2, rp, col, Hagg, M);
        ngemm_g<128, true, true, false><<<M / 64, 256, 0, stream>>>(Hagg, wt2b, b2_2, rp, H);
        pool_k<<<512, 128, 0, stream>>>(H, batch, psum, M, 512);
        head_g<<<GRAPHS, 256, 0, stream>>>(psum, gs, wm1, bm1, wm2, bm2, (float*)d_out);
    }
}

// Round 10
// 342.950 us; speedup vs baseline: 4.0732x; 4.0732x over previous
//
#include <hip/hip_runtime.h>
#include <cstdint>
#include <cstddef>

// GNNEncoder: 2x (edge-MLP GNN layer) + mean pool + MLP head. bf16 node pipeline.
// R10: discrete launches only (grid.sync costs ~200us on MI355X - R9 lesson).
// 9 dispatches: setup -> hist||AB1 -> scan -> fill -> agg1 -> layer(H1+AB2)
//               -> agg2 -> H2+pool(fused, H never hits global) -> head.

static constexpr int GRAPHS = 64;

using bf16x8 = __attribute__((ext_vector_type(8))) short;
using f32x4 = __attribute__((ext_vector_type(4))) float;

__device__ inline float bf2f(uint u) { return __builtin_bit_cast(float, u << 16); }
__device__ inline float bf2f_hi(uint u) { return __builtin_bit_cast(float, u & 0xffff0000u); }
__device__ inline ushort f2bf(float f) {
    uint u = __builtin_bit_cast(uint, f);
    return (ushort)((u + 0x7fffu + ((u >> 16) & 1u)) >> 16);
}

union SM {
    uint4 xt[64 * 17];               // node tile, padded row stride 17*16B
    struct { float p[128]; float h[128]; } hd;
};

// ---------------- shared device bodies ----------------
template <bool F32IN>
__device__ __forceinline__ void stage_tile(SM& sm, const void* Xin, int node0) {
    int t = threadIdx.x;
    int row = t >> 2;
#pragma unroll
    for (int i = 0; i < 4; ++i) {
        int chunk = (t & 3) + i * 4;
        uint4 v;
        if constexpr (F32IN) {
            const float* s = (const float*)Xin + (size_t)(node0 + row) * 128 + chunk * 8;
            float4 v0 = *reinterpret_cast<const float4*>(s);
            float4 v1 = *reinterpret_cast<const float4*>(s + 4);
            uint* vu = reinterpret_cast<uint*>(&v);
            vu[0] = (uint)f2bf(v0.x) | ((uint)f2bf(v0.y) << 16);
            vu[1] = (uint)f2bf(v0.z) | ((uint)f2bf(v0.w) << 16);
            vu[2] = (uint)f2bf(v1.x) | ((uint)f2bf(v1.y) << 16);
            vu[3] = (uint)f2bf(v1.z) | ((uint)f2bf(v1.w) << 16);
        } else {
            v = *reinterpret_cast<const uint4*>((const ushort*)Xin + (size_t)(node0 + row) * 128 + chunk * 8);
        }
        sm.xt[row * 17 + chunk] = v;
    }
}

template <int NOUT, bool RELU, bool DEGBIAS>
__device__ __forceinline__ void ngemm_compute(SM& sm, const ushort* Wt, const float* bias,
                                              const int* rp, ushort* Y, int node0) {
    int t = threadIdx.x;
    int lane = t & 63, wv = t >> 6;
    int lr = lane & 15, lg = lane >> 4;

    bf16x8 bfr[4][4];
#pragma unroll
    for (int rs = 0; rs < 4; ++rs)
#pragma unroll
        for (int kk = 0; kk < 4; ++kk)
            bfr[rs][kk] = *reinterpret_cast<const bf16x8*>(&sm.xt[(rs * 16 + lr) * 17 + lg + 4 * kk]);

    float degf[4];
    if constexpr (DEGBIAS) {
#pragma unroll
        for (int rs = 0; rs < 4; ++rs) {
            int r_ = node0 + rs * 16 + lr;
            degf[rs] = (float)(rp[r_ + 1] - rp[r_]);
        }
    }

    constexpr int NBW = NOUT / 64;
#pragma unroll
    for (int q = 0; q < NBW; ++q) {
        int nb = wv * NBW + q;
        const ushort* wrow = Wt + (size_t)(nb * 16 + lr) * 128 + lg * 8;
        bf16x8 af[4];
#pragma unroll
        for (int kk = 0; kk < 4; ++kk) af[kk] = *reinterpret_cast<const bf16x8*>(wrow + kk * 32);
        float4 bb = *reinterpret_cast<const float4*>(bias + nb * 16 + lg * 4);
        const float* bbp = reinterpret_cast<const float*>(&bb);
#pragma unroll
        for (int rs = 0; rs < 4; ++rs) {
            f32x4 acc = {0.f, 0.f, 0.f, 0.f};
#pragma unroll
            for (int kk = 0; kk < 4; ++kk)
                acc = __builtin_amdgcn_mfma_f32_16x16x32_bf16(af[kk], bfr[rs][kk], acc, 0, 0, 0);
            ushort4 o;
#pragma unroll
            for (int r = 0; r < 4; ++r) {
                float v = acc[r] + (DEGBIAS ? degf[rs] * bbp[r] : bbp[r]);
                if constexpr (RELU) v = fmaxf(v, 0.f);
                reinterpret_cast<ushort*>(&o)[r] = f2bf(v);
            }
            *reinterpret_cast<ushort4*>(Y + (size_t)(node0 + rs * 16 + lr) * NOUT + nb * 16 + lg * 4) = o;
        }
    }
}

template <int NOUT, bool RELU, bool DEGBIAS, bool F32IN>
__device__ __forceinline__ void ngemm_tile(SM& sm, const void* Xin, const ushort* Wt,
                                           const float* bias, const int* rp, ushort* Y, int node0) {
    stage_tile<F32IN>(sm, Xin, node0);
    __syncthreads();
    ngemm_compute<NOUT, RELU, DEGBIAS>(sm, Wt, bias, rp, Y, node0);
}

// fused: H1 = relu(Hagg@W2t^T + deg*b2) in regs -> LDS -> AB2 = H1@W1n^T + bn
__device__ __forceinline__ void layer_tile(SM& sm, const ushort* Hagg,
                                           const ushort* W2t, const float* b2,
                                           const ushort* W1n, const float* bn,
                                           const int* rp, ushort* AB2, int node0) {
    stage_tile<false>(sm, Hagg, node0);
    __syncthreads();
    int t = threadIdx.x;
    int lane = t & 63, wv = t >> 6;
    int lr = lane & 15, lg = lane >> 4;

    bf16x8 bfr[4][4];
#pragma unroll
    for (int rs = 0; rs < 4; ++rs)
#pragma unroll
        for (int kk = 0; kk < 4; ++kk)
            bfr[rs][kk] = *reinterpret_cast<const bf16x8*>(&sm.xt[(rs * 16 + lr) * 17 + lg + 4 * kk]);

    float degf[4];
#pragma unroll
    for (int rs = 0; rs < 4; ++rs) {
        int r_ = node0 + rs * 16 + lr;
        degf[rs] = (float)(rp[r_ + 1] - rp[r_]);
    }

    ushort4 h1o[2][4];
#pragma unroll
    for (int q = 0; q < 2; ++q) {
        int nb = wv * 2 + q;
        const ushort* wrow = W2t + (size_t)(nb * 16 + lr) * 128 + lg * 8;
        bf16x8 af[4];
#pragma unroll
        for (int kk = 0; kk < 4; ++kk) af[kk] = *reinterpret_cast<const bf16x8*>(wrow + kk * 32);
        float4 bb = *reinterpret_cast<const float4*>(b2 + nb * 16 + lg * 4);
        const float* bbp = reinterpret_cast<const float*>(&bb);
#pragma unroll
        for (int rs = 0; rs < 4; ++rs) {
            f32x4 acc = {0.f, 0.f, 0.f, 0.f};
#pragma unroll
            for (int kk = 0; kk < 4; ++kk)
                acc = __builtin_amdgcn_mfma_f32_16x16x32_bf16(af[kk], bfr[rs][kk], acc, 0, 0, 0);
#pragma unroll
            for (int r = 0; r < 4; ++r) {
                float v = fmaxf(acc[r] + degf[rs] * bbp[r], 0.f);
                reinterpret_cast<ushort*>(&h1o[q][rs])[r] = f2bf(v);
            }
        }
    }
    __syncthreads();
    char* xb = reinterpret_cast<char*>(sm.xt);
#pragma unroll
    for (int q = 0; q < 2; ++q)
#pragma unroll
        for (int rs = 0; rs < 4; ++rs) {
            int row = rs * 16 + lr;
            int colc = (wv * 2 + q) * 16 + lg * 4;
            *reinterpret_cast<ushort4*>(xb + row * 272 + (colc >> 3) * 16 + (colc & 7) * 2) = h1o[q][rs];
        }
    __syncthreads();
    ngemm_compute<256, false, false>(sm, W1n, bn, nullptr, AB2, node0);
}

__device__ __forceinline__ void accum8(uint4 b, const float2* a, float2* acc) {
    const uint* bu = reinterpret_cast<const uint*>(&b);
#pragma unroll
    for (int j = 0; j < 4; ++j) {
        uint u = bu[j];
        acc[j].x += fmaxf(a[j].x + bf2f(u), 0.f);
        acc[j].y += fmaxf(a[j].y + bf2f_hi(u), 0.f);
    }
}

__device__ __forceinline__ void agg_node(const ushort* AB, const int* rp, const int* col,
                                         ushort* Hagg, int n, int lane) {
    int fs = lane & 15;
    int lg = lane >> 4;
    uint4 av = *reinterpret_cast<const uint4*>(AB + (size_t)n * 256 + fs * 8);
    float2 a[4];
    {
        const uint* au = reinterpret_cast<const uint*>(&av);
#pragma unroll
        for (int j = 0; j < 4; ++j) a[j] = make_float2(bf2f(au[j]), bf2f_hi(au[j]));
    }
    float2 acc[4] = {{0.f, 0.f}, {0.f, 0.f}, {0.f, 0.f}, {0.f, 0.f}};
    int e0 = rp[n], e1 = rp[n + 1];
    int eMain = e0 + ((e1 - e0) & ~7);
    for (int eb = e0; eb < eMain; eb += 8) {
        int sA = col[eb + lg];
        int sB = col[eb + lg + 4];
        uint4 bA = *reinterpret_cast<const uint4*>(AB + (size_t)sA * 256 + 128 + fs * 8);
        uint4 bB = *reinterpret_cast<const uint4*>(AB + (size_t)sB * 256 + 128 + fs * 8);
        accum8(bA, a, acc);
        accum8(bB, a, acc);
    }
    for (int e = eMain + lg; e < e1; e += 4) {
        int s = col[e];
        uint4 b = *reinterpret_cast<const uint4*>(AB + (size_t)s * 256 + 128 + fs * 8);
        accum8(b, a, acc);
    }
#pragma unroll
    for (int j = 0; j < 4; ++j) {
        acc[j].x += __shfl_xor(acc[j].x, 16);
        acc[j].y += __shfl_xor(acc[j].y, 16);
        acc[j].x += __shfl_xor(acc[j].x, 32);
        acc[j].y += __shfl_xor(acc[j].y, 32);
    }
    if (lg == 0) {
        uint4 o;
        uint* ou = reinterpret_cast<uint*>(&o);
#pragma unroll
        for (int j = 0; j < 4; ++j)
            ou[j] = (uint)f2bf(acc[j].x) | ((uint)f2bf(acc[j].y) << 16);
        *reinterpret_cast<uint4*>(Hagg + (size_t)n * 128 + fs * 8) = o;
    }
}

// ---------------- kernels ----------------
__global__ __launch_bounds__(256) void setup_k(
    const float* __restrict__ w1_1, const float* __restrict__ w2_1,
    const float* __restrict__ w1_2, const float* __restrict__ w2_2,
    const float* __restrict__ b1_1, const float* __restrict__ b2_1,
    ushort* __restrict__ wt1a, ushort* __restrict__ wt1b,
    ushort* __restrict__ wt2a, ushort* __restrict__ wt2b,
    float* __restrict__ b256_1, float* __restrict__ b256_2,
    int* __restrict__ deg, float* __restrict__ psum,
    const int* __restrict__ batch, int* __restrict__ gs, int M, int nbDeg) {
    int b = blockIdx.x, t = threadIdx.x;
    if (b < 128) {
        int i = b * 256 + t;
        int j = i >> 7, k = i & 127;
        wt1a[i] = f2bf((j < 128) ? w1_1[k * 128 + j] : w1_1[(128 + k) * 128 + (j - 128)]);
        wt1b[i] = f2bf((j < 128) ? w2_1[k * 128 + j] : w2_1[(128 + k) * 128 + (j - 128)]);
        return;
    }
    b -= 128;
    if (b < 64) {
        int i = b * 256 + t;
        int j = i >> 7, k = i & 127;
        wt2a[i] = f2bf(w1_2[k * 128 + j]);
        wt2b[i] = f2bf(w2_2[k * 128 + j]);
        return;
    }
    b -= 64;
    if (b < nbDeg) {
        int i = b * 256 + t;
        if (i < M) deg[i] = 0;
        return;
    }
    b -= nbDeg;
    if (b < 32) {
        psum[b * 256 + t] = 0.f;
        return;
    }
    b -= 32;
    if (b == 0) {
        b256_1[t] = (t < 128) ? b1_1[t] : 0.f;
        b256_2[t] = (t < 128) ? b2_1[t] : 0.f;
        return;
    }
    if (t > GRAPHS) return;
    int lo = 0, hi = M;
    while (lo < hi) {
        int mid = (lo + hi) >> 1;
        if (batch[mid] < t) lo = mid + 1;
        else hi = mid;
    }
    gs[t] = lo;
}

// hist (blocks [0,HB)) in parallel with layer1 edge-GEMM (blocks [HB, HB+M/64))
__global__ __launch_bounds__(256) void histgemm_k(const int* __restrict__ dst, int* __restrict__ deg,
                                                  int E, int HB,
                                                  const float* __restrict__ x,
                                                  const ushort* __restrict__ wt1a,
                                                  const float* __restrict__ b256_1,
                                                  ushort* __restrict__ AB1) {
    __shared__ SM sm;
    int b = blockIdx.x;
    if (b < HB) {
        for (int i = b * 256 + threadIdx.x; i < E; i += HB * 256)
            atomicAdd(&deg[dst[i]], 1);
        return;
    }
    ngemm_tile<256, false, false, true>(sm, x, wt1a, b256_1, nullptr, AB1, (b - HB) * 64);
}

__global__ __launch_bounds__(256) void scan_k(const int* __restrict__ deg, int* __restrict__ rp,
                                              int* __restrict__ cursor, int M) {
    __shared__ int ts[256];
    int t = threadIdx.x;
    int per = (M + 255) / 256;
    per = (per + 3) & ~3;
    int s0 = t * per;
    int s1 = s0 + per; if (s1 > M) s1 = M;
    int sum = 0;
    for (int i = s0; i < s1; i += 4) {
        int4 v = *reinterpret_cast<const int4*>(deg + i);
        sum += v.x + v.y + v.z + v.w;
    }
    ts[t] = sum;
    __syncthreads();
    for (int off = 1; off < 256; off <<= 1) {
        int v = (t >= off) ? ts[t - off] : 0;
        __syncthreads();
        ts[t] += v;
        __syncthreads();
    }
    int run = ts[t] - sum;
    for (int i = s0; i < s1; i += 4) {
        int4 v = *reinterpret_cast<const int4*>(deg + i);
        int4 o;
        o.x = run; run += v.x;
        o.y = run; run += v.y;
        o.z = run; run += v.z;
        o.w = run; run += v.w;
        *reinterpret_cast<int4*>(rp + i) = o;
        *reinterpret_cast<int4*>(cursor + i) = o;
    }
    if (t == 0) rp[M] = ts[255];
}

__global__ __launch_bounds__(256) void fill_k(const int* __restrict__ src, const int* __restrict__ dst,
                                              int* __restrict__ cursor, int* __restrict__ col, int E) {
    int i = blockIdx.x * 256 + threadIdx.x;
    if (i < E) {
        int d = dst[i];
        int p = atomicAdd(&cursor[d], 1);
        col[p] = src[i];
    }
}

__global__ __launch_bounds__(256) void agg_g(const ushort* __restrict__ AB, const int* __restrict__ rp,
                                             const int* __restrict__ col, ushort* __restrict__ Hagg, int M) {
    int lane = threadIdx.x & 63, wv = threadIdx.x >> 6;
    int n = blockIdx.x * 4 + wv;
    if (n < M) agg_node(AB, rp, col, Hagg, n, lane);
}

__global__ __launch_bounds__(256) void layer_g(const ushort* __restrict__ Hagg,
                                               const ushort* __restrict__ W2t, const float* __restrict__ b2,
                                               const ushort* __restrict__ W1n, const float* __restrict__ bn,
                                               const int* __restrict__ rp, ushort* __restrict__ AB2) {
    __shared__ SM sm;
    layer_tile(sm, Hagg, W2t, b2, W1n, bn, rp, AB2, blockIdx.x * 64);
}

// H2-GEMM + fused mean-pool partials (H never written to global).
__global__ __launch_bounds__(256) void h2pool_k(const ushort* __restrict__ Hagg,
                                                const ushort* __restrict__ Wt, const float* __restrict__ bias,
                                                const int* __restrict__ rp, const int* __restrict__ batch,
                                                float* __restrict__ psum) {
    __shared__ SM sm;
    int node0 = blockIdx.x * 64;
    stage_tile<false>(sm, Hagg, node0);
    __syncthreads();

    int t = threadIdx.x;
    int lane = t & 63, wv = t >> 6;
    int lr = lane & 15, lg = lane >> 4;

    bf16x8 bfr[4][4];
#pragma unroll
    for (int rs = 0; rs < 4; ++rs)
#pragma unroll
        for (int kk = 0; kk < 4; ++kk)
            bfr[rs][kk] = *reinterpret_cast<const bf16x8*>(&sm.xt[(rs * 16 + lr) * 17 + lg + 4 * kk]);

    float degf[4];
#pragma unroll
    for (int rs = 0; rs < 4; ++rs) {
        int r_ = node0 + rs * 16 + lr;
        degf[rs] = (float)(rp[r_ + 1] - rp[r_]);
    }

    int gLo = batch[node0], gHi = batch[node0 + 63];
    bool uniform = (gLo == gHi);

    float s[2][4];
#pragma unroll
    for (int q = 0; q < 2; ++q)
#pragma unroll
        for (int r = 0; r < 4; ++r) s[q][r] = 0.f;

#pragma unroll
    for (int q = 0; q < 2; ++q) {
        int nb = wv * 2 + q;
        const ushort* wrow = Wt + (size_t)(nb * 16 + lr) * 128 + lg * 8;
        bf16x8 af[4];
#pragma unroll
        for (int kk = 0; kk < 4; ++kk) af[kk] = *reinterpret_cast<const bf16x8*>(wrow + kk * 32);
        float4 bb = *reinterpret_cast<const float4*>(bias + nb * 16 + lg * 4);
        const float* bbp = reinterpret_cast<const float*>(&bb);
#pragma unroll
        for (int rs = 0; rs < 4; ++rs) {
            f32x4 acc = {0.f, 0.f, 0.f, 0.f};
#pragma unroll
            for (int kk = 0; kk < 4; ++kk)
                acc = __builtin_amdgcn_mfma_f32_16x16x32_bf16(af[kk], bfr[rs][kk], acc, 0, 0, 0);
            if (uniform) {
#pragma unroll
                for (int r = 0; r < 4; ++r)
                    s[q][r] += fmaxf(acc[r] + degf[rs] * bbp[r], 0.f);
            } else {
                int g = batch[node0 + rs * 16 + lr];
#pragma unroll
                for (int r = 0; r < 4; ++r) {
                    float v = fmaxf(acc[r] + degf[rs] * bbp[r], 0.f);
                    atomicAdd(&psum[g * 128 + nb * 16 + lg * 4 + r], v);
                }
            }
        }
    }
    if (uniform) {
#pragma unroll
        for (int q = 0; q < 2; ++q)
#pragma unroll
            for (int r = 0; r < 4; ++r) {
                s[q][r] += __shfl_xor(s[q][r], 1);
                s[q][r] += __shfl_xor(s[q][r], 2);
                s[q][r] += __shfl_xor(s[q][r], 4);
                s[q][r] += __shfl_xor(s[q][r], 8);
            }
        if (lr == 0) {
#pragma unroll
            for (int q = 0; q < 2; ++q)
#pragma unroll
                for (int r = 0; r < 4; ++r)
                    atomicAdd(&psum[gLo * 128 + (wv * 2 + q) * 16 + lg * 4 + r], s[q][r]);
        }
    }
}

__global__ __launch_bounds__(256) void head_g(const float* __restrict__ psum, const int* __restrict__ gs,
                                              const float* __restrict__ wm1, const float* __restrict__ bm1,
                                              const float* __restrict__ wm2, const float* __restrict__ bm2,
                                              float* __restrict__ out) {
    __shared__ SM sm;
    int g = blockIdx.x, t = threadIdx.x;
    int cnt = gs[g + 1] - gs[g];
    float rcp = 1.0f / (float)(cnt > 0 ? cnt : 1);
    if (t < 128) sm.hd.p[t] = psum[g * 128 + t] * rcp;
    __syncthreads();
    if (t < 128) {
        float a = bm1[t];
        for (int k = 0; k < 128; ++k) a += sm.hd.p[k] * wm1[k * 128 + t];
        sm.hd.h[t] = fmaxf(a, 0.f);
    }
    __syncthreads();
    if (t < 128) {
        float acc[4];
#pragma unroll
        for (int j = 0; j < 4; ++j) acc[j] = bm2[j * 128 + t];
        for (int k = 0; k < 128; ++k) {
            float hv = sm.hd.h[k];
#pragma unroll
            for (int j = 0; j < 4; ++j) acc[j] += hv * wm2[k * 512 + j * 128 + t];
        }
#pragma unroll
        for (int j = 0; j < 4; ++j) out[(size_t)g * 512 + j * 128 + t] = acc[j];
    }
}

extern "C" void kernel_launch(void* const* d_in, const int* in_sizes, int n_in,
                              void* d_out, int out_size, void* d_ws, size_t ws_size,
                              hipStream_t stream) {
    const float* x = (const float*)d_in[0];
    const int* ei = (const int*)d_in[1];
    const int* batch = (const int*)d_in[2];
    const float* w1_1 = (const float*)d_in[3];
    const float* b1_1 = (const float*)d_in[4];
    const float* w1_2 = (const float*)d_in[5];
    const float* b1_2 = (const float*)d_in[6];
    const float* w2_1 = (const float*)d_in[7];
    const float* b2_1 = (const float*)d_in[8];
    const float* w2_2 = (const float*)d_in[9];
    const float* b2_2 = (const float*)d_in[10];
    const float* wm1 = (const float*)d_in[11];
    const float* bm1 = (const float*)d_in[12];
    const float* wm2 = (const float*)d_in[13];
    const float* bm2 = (const float*)d_in[14];

    const int E = in_sizes[1] / 2;
    const int M = in_sizes[0] / 128;
    const int* srcp = ei;
    const int* dstp = ei + E;

    char* ws = (char*)d_ws;
    size_t off = 0;
    auto alloc = [&](size_t bytes) -> void* {
        void* ptr = ws + off;
        off += (bytes + 255) & ~(size_t)255;
        return ptr;
    };
    ushort* AB1 = (ushort*)alloc((size_t)M * 256 * 2);
    ushort* AB2 = (ushort*)alloc((size_t)M * 256 * 2);
    ushort* Hagg = (ushort*)alloc((size_t)M * 128 * 2);
    int* rp = (int*)alloc((size_t)(M + 1) * 4);
    int* cursor = (int*)alloc((size_t)M * 4);   // deg during hist, bump cursor during fill
    int* col = (int*)alloc((size_t)E * 4);
    int* gs = (int*)alloc((GRAPHS + 1) * 4);
    float* psum = (float*)alloc(GRAPHS * 128 * 4);
    ushort* wt1a = (ushort*)alloc(256 * 128 * 2);
    ushort* wt1b = (ushort*)alloc(256 * 128 * 2);
    ushort* wt2a = (ushort*)alloc(128 * 128 * 2);
    ushort* wt2b = (ushort*)alloc(128 * 128 * 2);
    float* b256_1 = (float*)alloc(256 * 4);
    float* b256_2 = (float*)alloc(256 * 4);

    const int nbDeg = (M + 255) / 256;
    const int HB = 512;

    // 1. setup
    setup_k<<<128 + 64 + nbDeg + 32 + 2, 256, 0, stream>>>(
        w1_1, w2_1, w1_2, w2_2, b1_1, b2_1, wt1a, wt1b, wt2a, wt2b, b256_1, b256_2,
        cursor, psum, batch, gs, M, nbDeg);
    // 2. hist || layer1 edge-GEMM
    histgemm_k<<<HB + M / 64, 256, 0, stream>>>(dstp, cursor, E, HB, x, wt1a, b256_1, AB1);
    // 3. scan
    scan_k<<<1, 256, 0, stream>>>(cursor, rp, cursor, M);
    // 4. fill
    fill_k<<<(E + 255) / 256, 256, 0, stream>>>(srcp, dstp, cursor, col, E);
    // 5. agg layer1
    agg_g<<<(M + 3) / 4, 256, 0, stream>>>(AB1, rp, col, Hagg, M);
    // 6. fused H1-GEMM + layer2 edge-GEMM
    layer_g<<<M / 64, 256, 0, stream>>>(Hagg, wt2a, b1_2, wt1b, b256_2, rp, AB2);
    // 7. agg layer2
    agg_g<<<(M + 3) / 4, 256, 0, stream>>>(AB2, rp, col, Hagg, M);
    // 8. H2-GEMM + fused pool
    h2pool_k<<<M / 64, 256, 0, stream>>>(Hagg, wt2b, b2_2, rp, batch, psum);
    // 9. head
    head_g<<<GRAPHS, 256, 0, stream>>>(psum, gs, wm1, bm1, wm2, bm2, (float*)d_out);
}

// Round 11
// 205.388 us; speedup vs baseline: 6.8013x; 1.6698x over previous
//
#include <hip/hip_runtime.h>
#include <cstdint>
#include <cstddef>

// GNNEncoder: 2x (edge-MLP GNN layer) + mean pool + MLP head. bf16 node pipeline.
// R11: 9 dispatches (R10 structure). h2pool boundary-tile fix: two-accumulator
// (lo/hi graph) register reduce -> 256 atomics, instead of 8192 per-row atomics
// (R10's 516K cross-XCD atomics = 150us). Slow path only for >=3-graph tiles.

static constexpr int GRAPHS = 64;

using bf16x8 = __attribute__((ext_vector_type(8))) short;
using f32x4 = __attribute__((ext_vector_type(4))) float;

__device__ inline float bf2f(uint u) { return __builtin_bit_cast(float, u << 16); }
__device__ inline float bf2f_hi(uint u) { return __builtin_bit_cast(float, u & 0xffff0000u); }
__device__ inline ushort f2bf(float f) {
    uint u = __builtin_bit_cast(uint, f);
    return (ushort)((u + 0x7fffu + ((u >> 16) & 1u)) >> 16);
}

union SM {
    uint4 xt[64 * 17];               // node tile, padded row stride 17*16B
    struct { float p[128]; float h[128]; } hd;
};

// ---------------- shared device bodies ----------------
template <bool F32IN>
__device__ __forceinline__ void stage_tile(SM& sm, const void* Xin, int node0) {
    int t = threadIdx.x;
    int row = t >> 2;
#pragma unroll
    for (int i = 0; i < 4; ++i) {
        int chunk = (t & 3) + i * 4;
        uint4 v;
        if constexpr (F32IN) {
            const float* s = (const float*)Xin + (size_t)(node0 + row) * 128 + chunk * 8;
            float4 v0 = *reinterpret_cast<const float4*>(s);
            float4 v1 = *reinterpret_cast<const float4*>(s + 4);
            uint* vu = reinterpret_cast<uint*>(&v);
            vu[0] = (uint)f2bf(v0.x) | ((uint)f2bf(v0.y) << 16);
            vu[1] = (uint)f2bf(v0.z) | ((uint)f2bf(v0.w) << 16);
            vu[2] = (uint)f2bf(v1.x) | ((uint)f2bf(v1.y) << 16);
            vu[3] = (uint)f2bf(v1.z) | ((uint)f2bf(v1.w) << 16);
        } else {
            v = *reinterpret_cast<const uint4*>((const ushort*)Xin + (size_t)(node0 + row) * 128 + chunk * 8);
        }
        sm.xt[row * 17 + chunk] = v;
    }
}

template <int NOUT, bool RELU, bool DEGBIAS>
__device__ __forceinline__ void ngemm_compute(SM& sm, const ushort* Wt, const float* bias,
                                              const int* rp, ushort* Y, int node0) {
    int t = threadIdx.x;
    int lane = t & 63, wv = t >> 6;
    int lr = lane & 15, lg = lane >> 4;

    bf16x8 bfr[4][4];
#pragma unroll
    for (int rs = 0; rs < 4; ++rs)
#pragma unroll
        for (int kk = 0; kk < 4; ++kk)
            bfr[rs][kk] = *reinterpret_cast<const bf16x8*>(&sm.xt[(rs * 16 + lr) * 17 + lg + 4 * kk]);

    float degf[4];
    if constexpr (DEGBIAS) {
#pragma unroll
        for (int rs = 0; rs < 4; ++rs) {
            int r_ = node0 + rs * 16 + lr;
            degf[rs] = (float)(rp[r_ + 1] - rp[r_]);
        }
    }

    constexpr int NBW = NOUT / 64;
#pragma unroll
    for (int q = 0; q < NBW; ++q) {
        int nb = wv * NBW + q;
        const ushort* wrow = Wt + (size_t)(nb * 16 + lr) * 128 + lg * 8;
        bf16x8 af[4];
#pragma unroll
        for (int kk = 0; kk < 4; ++kk) af[kk] = *reinterpret_cast<const bf16x8*>(wrow + kk * 32);
        float4 bb = *reinterpret_cast<const float4*>(bias + nb * 16 + lg * 4);
        const float* bbp = reinterpret_cast<const float*>(&bb);
#pragma unroll
        for (int rs = 0; rs < 4; ++rs) {
            f32x4 acc = {0.f, 0.f, 0.f, 0.f};
#pragma unroll
            for (int kk = 0; kk < 4; ++kk)
                acc = __builtin_amdgcn_mfma_f32_16x16x32_bf16(af[kk], bfr[rs][kk], acc, 0, 0, 0);
            ushort4 o;
#pragma unroll
            for (int r = 0; r < 4; ++r) {
                float v = acc[r] + (DEGBIAS ? degf[rs] * bbp[r] : bbp[r]);
                if constexpr (RELU) v = fmaxf(v, 0.f);
                reinterpret_cast<ushort*>(&o)[r] = f2bf(v);
            }
            *reinterpret_cast<ushort4*>(Y + (size_t)(node0 + rs * 16 + lr) * NOUT + nb * 16 + lg * 4) = o;
        }
    }
}

template <int NOUT, bool RELU, bool DEGBIAS, bool F32IN>
__device__ __forceinline__ void ngemm_tile(SM& sm, const void* Xin, const ushort* Wt,
                                           const float* bias, const int* rp, ushort* Y, int node0) {
    stage_tile<F32IN>(sm, Xin, node0);
    __syncthreads();
    ngemm_compute<NOUT, RELU, DEGBIAS>(sm, Wt, bias, rp, Y, node0);
}

// fused: H1 = relu(Hagg@W2t^T + deg*b2) in regs -> LDS -> AB2 = H1@W1n^T + bn
__device__ __forceinline__ void layer_tile(SM& sm, const ushort* Hagg,
                                           const ushort* W2t, const float* b2,
                                           const ushort* W1n, const float* bn,
                                           const int* rp, ushort* AB2, int node0) {
    stage_tile<false>(sm, Hagg, node0);
    __syncthreads();
    int t = threadIdx.x;
    int lane = t & 63, wv = t >> 6;
    int lr = lane & 15, lg = lane >> 4;

    bf16x8 bfr[4][4];
#pragma unroll
    for (int rs = 0; rs < 4; ++rs)
#pragma unroll
        for (int kk = 0; kk < 4; ++kk)
            bfr[rs][kk] = *reinterpret_cast<const bf16x8*>(&sm.xt[(rs * 16 + lr) * 17 + lg + 4 * kk]);

    float degf[4];
#pragma unroll
    for (int rs = 0; rs < 4; ++rs) {
        int r_ = node0 + rs * 16 + lr;
        degf[rs] = (float)(rp[r_ + 1] - rp[r_]);
    }

    ushort4 h1o[2][4];
#pragma unroll
    for (int q = 0; q < 2; ++q) {
        int nb = wv * 2 + q;
        const ushort* wrow = W2t + (size_t)(nb * 16 + lr) * 128 + lg * 8;
        bf16x8 af[4];
#pragma unroll
        for (int kk = 0; kk < 4; ++kk) af[kk] = *reinterpret_cast<const bf16x8*>(wrow + kk * 32);
        float4 bb = *reinterpret_cast<const float4*>(b2 + nb * 16 + lg * 4);
        const float* bbp = reinterpret_cast<const float*>(&bb);
#pragma unroll
        for (int rs = 0; rs < 4; ++rs) {
            f32x4 acc = {0.f, 0.f, 0.f, 0.f};
#pragma unroll
            for (int kk = 0; kk < 4; ++kk)
                acc = __builtin_amdgcn_mfma_f32_16x16x32_bf16(af[kk], bfr[rs][kk], acc, 0, 0, 0);
#pragma unroll
            for (int r = 0; r < 4; ++r) {
                float v = fmaxf(acc[r] + degf[rs] * bbp[r], 0.f);
                reinterpret_cast<ushort*>(&h1o[q][rs])[r] = f2bf(v);
            }
        }
    }
    __syncthreads();
    char* xb = reinterpret_cast<char*>(sm.xt);
#pragma unroll
    for (int q = 0; q < 2; ++q)
#pragma unroll
        for (int rs = 0; rs < 4; ++rs) {
            int row = rs * 16 + lr;
            int colc = (wv * 2 + q) * 16 + lg * 4;
            *reinterpret_cast<ushort4*>(xb + row * 272 + (colc >> 3) * 16 + (colc & 7) * 2) = h1o[q][rs];
        }
    __syncthreads();
    ngemm_compute<256, false, false>(sm, W1n, bn, nullptr, AB2, node0);
}

__device__ __forceinline__ void accum8(uint4 b, const float2* a, float2* acc) {
    const uint* bu = reinterpret_cast<const uint*>(&b);
#pragma unroll
    for (int j = 0; j < 4; ++j) {
        uint u = bu[j];
        acc[j].x += fmaxf(a[j].x + bf2f(u), 0.f);
        acc[j].y += fmaxf(a[j].y + bf2f_hi(u), 0.f);
    }
}

__device__ __forceinline__ void agg_node(const ushort* AB, const int* rp, const int* col,
                                         ushort* Hagg, int n, int lane) {
    int fs = lane & 15;
    int lg = lane >> 4;
    uint4 av = *reinterpret_cast<const uint4*>(AB + (size_t)n * 256 + fs * 8);
    float2 a[4];
    {
        const uint* au = reinterpret_cast<const uint*>(&av);
#pragma unroll
        for (int j = 0; j < 4; ++j) a[j] = make_float2(bf2f(au[j]), bf2f_hi(au[j]));
    }
    float2 acc[4] = {{0.f, 0.f}, {0.f, 0.f}, {0.f, 0.f}, {0.f, 0.f}};
    int e0 = rp[n], e1 = rp[n + 1];
    int eMain = e0 + ((e1 - e0) & ~7);
    for (int eb = e0; eb < eMain; eb += 8) {
        int sA = col[eb + lg];
        int sB = col[eb + lg + 4];
        uint4 bA = *reinterpret_cast<const uint4*>(AB + (size_t)sA * 256 + 128 + fs * 8);
        uint4 bB = *reinterpret_cast<const uint4*>(AB + (size_t)sB * 256 + 128 + fs * 8);
        accum8(bA, a, acc);
        accum8(bB, a, acc);
    }
    for (int e = eMain + lg; e < e1; e += 4) {
        int s = col[e];
        uint4 b = *reinterpret_cast<const uint4*>(AB + (size_t)s * 256 + 128 + fs * 8);
        accum8(b, a, acc);
    }
#pragma unroll
    for (int j = 0; j < 4; ++j) {
        acc[j].x += __shfl_xor(acc[j].x, 16);
        acc[j].y += __shfl_xor(acc[j].y, 16);
        acc[j].x += __shfl_xor(acc[j].x, 32);
        acc[j].y += __shfl_xor(acc[j].y, 32);
    }
    if (lg == 0) {
        uint4 o;
        uint* ou = reinterpret_cast<uint*>(&o);
#pragma unroll
        for (int j = 0; j < 4; ++j)
            ou[j] = (uint)f2bf(acc[j].x) | ((uint)f2bf(acc[j].y) << 16);
        *reinterpret_cast<uint4*>(Hagg + (size_t)n * 128 + fs * 8) = o;
    }
}

// ---------------- kernels ----------------
__global__ __launch_bounds__(256) void setup_k(
    const float* __restrict__ w1_1, const float* __restrict__ w2_1,
    const float* __restrict__ w1_2, const float* __restrict__ w2_2,
    const float* __restrict__ b1_1, const float* __restrict__ b2_1,
    ushort* __restrict__ wt1a, ushort* __restrict__ wt1b,
    ushort* __restrict__ wt2a, ushort* __restrict__ wt2b,
    float* __restrict__ b256_1, float* __restrict__ b256_2,
    int* __restrict__ deg, float* __restrict__ psum,
    const int* __restrict__ batch, int* __restrict__ gs, int M, int nbDeg) {
    int b = blockIdx.x, t = threadIdx.x;
    if (b < 128) {
        int i = b * 256 + t;
        int j = i >> 7, k = i & 127;
        wt1a[i] = f2bf((j < 128) ? w1_1[k * 128 + j] : w1_1[(128 + k) * 128 + (j - 128)]);
        wt1b[i] = f2bf((j < 128) ? w2_1[k * 128 + j] : w2_1[(128 + k) * 128 + (j - 128)]);
        return;
    }
    b -= 128;
    if (b < 64) {
        int i = b * 256 + t;
        int j = i >> 7, k = i & 127;
        wt2a[i] = f2bf(w1_2[k * 128 + j]);
        wt2b[i] = f2bf(w2_2[k * 128 + j]);
        return;
    }
    b -= 64;
    if (b < nbDeg) {
        int i = b * 256 + t;
        if (i < M) deg[i] = 0;
        return;
    }
    b -= nbDeg;
    if (b < 32) {
        psum[b * 256 + t] = 0.f;
        return;
    }
    b -= 32;
    if (b == 0) {
        b256_1[t] = (t < 128) ? b1_1[t] : 0.f;
        b256_2[t] = (t < 128) ? b2_1[t] : 0.f;
        return;
    }
    if (t > GRAPHS) return;
    int lo = 0, hi = M;
    while (lo < hi) {
        int mid = (lo + hi) >> 1;
        if (batch[mid] < t) lo = mid + 1;
        else hi = mid;
    }
    gs[t] = lo;
}

// hist (blocks [0,HB)) in parallel with layer1 edge-GEMM (blocks [HB, HB+M/64))
__global__ __launch_bounds__(256) void histgemm_k(const int* __restrict__ dst, int* __restrict__ deg,
                                                  int E, int HB,
                                                  const float* __restrict__ x,
                                                  const ushort* __restrict__ wt1a,
                                                  const float* __restrict__ b256_1,
                                                  ushort* __restrict__ AB1) {
    __shared__ SM sm;
    int b = blockIdx.x;
    if (b < HB) {
        for (int i = b * 256 + threadIdx.x; i < E; i += HB * 256)
            atomicAdd(&deg[dst[i]], 1);
        return;
    }
    ngemm_tile<256, false, false, true>(sm, x, wt1a, b256_1, nullptr, AB1, (b - HB) * 64);
}

__global__ __launch_bounds__(256) void scan_k(const int* __restrict__ deg, int* __restrict__ rp,
                                              int* __restrict__ cursor, int M) {
    __shared__ int ts[256];
    int t = threadIdx.x;
    int per = (M + 255) / 256;
    per = (per + 3) & ~3;
    int s0 = t * per;
    int s1 = s0 + per; if (s1 > M) s1 = M;
    int sum = 0;
    for (int i = s0; i < s1; i += 4) {
        int4 v = *reinterpret_cast<const int4*>(deg + i);
        sum += v.x + v.y + v.z + v.w;
    }
    ts[t] = sum;
    __syncthreads();
    for (int off = 1; off < 256; off <<= 1) {
        int v = (t >= off) ? ts[t - off] : 0;
        __syncthreads();
        ts[t] += v;
        __syncthreads();
    }
    int run = ts[t] - sum;
    for (int i = s0; i < s1; i += 4) {
        int4 v = *reinterpret_cast<const int4*>(deg + i);
        int4 o;
        o.x = run; run += v.x;
        o.y = run; run += v.y;
        o.z = run; run += v.z;
        o.w = run; run += v.w;
        *reinterpret_cast<int4*>(rp + i) = o;
        *reinterpret_cast<int4*>(cursor + i) = o;
    }
    if (t == 0) rp[M] = ts[255];
}

__global__ __launch_bounds__(256) void fill_k(const int* __restrict__ src, const int* __restrict__ dst,
                                              int* __restrict__ cursor, int* __restrict__ col, int E) {
    int i = blockIdx.x * 256 + threadIdx.x;
    if (i < E) {
        int d = dst[i];
        int p = atomicAdd(&cursor[d], 1);
        col[p] = src[i];
    }
}

__global__ __launch_bounds__(256) void agg_g(const ushort* __restrict__ AB, const int* __restrict__ rp,
                                             const int* __restrict__ col, ushort* __restrict__ Hagg, int M) {
    int lane = threadIdx.x & 63, wv = threadIdx.x >> 6;
    int n = blockIdx.x * 4 + wv;
    if (n < M) agg_node(AB, rp, col, Hagg, n, lane);
}

__global__ __launch_bounds__(256) void layer_g(const ushort* __restrict__ Hagg,
                                               const ushort* __restrict__ W2t, const float* __restrict__ b2,
                                               const ushort* __restrict__ W1n, const float* __restrict__ bn,
                                               const int* __restrict__ rp, ushort* __restrict__ AB2) {
    __shared__ SM sm;
    layer_tile(sm, Hagg, W2t, b2, W1n, bn, rp, AB2, blockIdx.x * 64);
}

// H2-GEMM + fused mean-pool partials. Tiles spanning <=2 graphs (the norm, batch
// sorted) use two register accumulators + 128/256 atomics; >=3-graph tiles fall
// back to per-row atomics (essentially never at ~625 nodes/graph).
__global__ __launch_bounds__(256) void h2pool_k(const ushort* __restrict__ Hagg,
                                                const ushort* __restrict__ Wt, const float* __restrict__ bias,
                                                const int* __restrict__ rp, const int* __restrict__ batch,
                                                float* __restrict__ psum) {
    __shared__ SM sm;
    int node0 = blockIdx.x * 64;
    stage_tile<false>(sm, Hagg, node0);
    __syncthreads();

    int t = threadIdx.x;
    int lane = t & 63, wv = t >> 6;
    int lr = lane & 15, lg = lane >> 4;

    bf16x8 bfr[4][4];
#pragma unroll
    for (int rs = 0; rs < 4; ++rs)
#pragma unroll
        for (int kk = 0; kk < 4; ++kk)
            bfr[rs][kk] = *reinterpret_cast<const bf16x8*>(&sm.xt[(rs * 16 + lr) * 17 + lg + 4 * kk]);

    float degf[4];
    int gnode[4];
#pragma unroll
    for (int rs = 0; rs < 4; ++rs) {
        int r_ = node0 + rs * 16 + lr;
        degf[rs] = (float)(rp[r_ + 1] - rp[r_]);
        gnode[rs] = batch[r_];
    }

    int gLo = batch[node0], gHi = batch[node0 + 63];
    bool two = (gHi - gLo) <= 1;   // tile spans at most 2 graphs

    float sLo[2][4], sHi[2][4];
#pragma unroll
    for (int q = 0; q < 2; ++q)
#pragma unroll
        for (int r = 0; r < 4; ++r) { sLo[q][r] = 0.f; sHi[q][r] = 0.f; }

#pragma unroll
    for (int q = 0; q < 2; ++q) {
        int nb = wv * 2 + q;
        const ushort* wrow = Wt + (size_t)(nb * 16 + lr) * 128 + lg * 8;
        bf16x8 af[4];
#pragma unroll
        for (int kk = 0; kk < 4; ++kk) af[kk] = *reinterpret_cast<const bf16x8*>(wrow + kk * 32);
        float4 bb = *reinterpret_cast<const float4*>(bias + nb * 16 + lg * 4);
        const float* bbp = reinterpret_cast<const float*>(&bb);
#pragma unroll
        for (int rs = 0; rs < 4; ++rs) {
            f32x4 acc = {0.f, 0.f, 0.f, 0.f};
#pragma unroll
            for (int kk = 0; kk < 4; ++kk)
                acc = __builtin_amdgcn_mfma_f32_16x16x32_bf16(af[kk], bfr[rs][kk], acc, 0, 0, 0);
            if (two) {
                bool isLo = (gnode[rs] == gLo);
#pragma unroll
                for (int r = 0; r < 4; ++r) {
                    float v = fmaxf(acc[r] + degf[rs] * bbp[r], 0.f);
                    if (isLo) sLo[q][r] += v;
                    else      sHi[q][r] += v;
                }
            } else {
#pragma unroll
                for (int r = 0; r < 4; ++r) {
                    float v = fmaxf(acc[r] + degf[rs] * bbp[r], 0.f);
                    atomicAdd(&psum[gnode[rs] * 128 + nb * 16 + lg * 4 + r], v);
                }
            }
        }
    }
    if (two) {
        bool split = (gHi != gLo);
#pragma unroll
        for (int q = 0; q < 2; ++q)
#pragma unroll
            for (int r = 0; r < 4; ++r) {
#pragma unroll
                for (int d = 1; d <= 8; d <<= 1) {
                    sLo[q][r] += __shfl_xor(sLo[q][r], d);
                    if (split) sHi[q][r] += __shfl_xor(sHi[q][r], d);
                }
            }
        if (lr == 0) {
#pragma unroll
            for (int q = 0; q < 2; ++q)
#pragma unroll
                for (int r = 0; r < 4; ++r) {
                    int f = (wv * 2 + q) * 16 + lg * 4 + r;
                    atomicAdd(&psum[gLo * 128 + f], sLo[q][r]);
                    if (split) atomicAdd(&psum[gHi * 128 + f], sHi[q][r]);
                }
        }
    }
}

__global__ __launch_bounds__(256) void head_g(const float* __restrict__ psum, const int* __restrict__ gs,
                                              const float* __restrict__ wm1, const float* __restrict__ bm1,
                                              const float* __restrict__ wm2, const float* __restrict__ bm2,
                                              float* __restrict__ out) {
    __shared__ SM sm;
    int g = blockIdx.x, t = threadIdx.x;
    int cnt = gs[g + 1] - gs[g];
    float rcp = 1.0f / (float)(cnt > 0 ? cnt : 1);
    if (t < 128) sm.hd.p[t] = psum[g * 128 + t] * rcp;
    __syncthreads();
    if (t < 128) {
        float a = bm1[t];
        for (int k = 0; k < 128; ++k) a += sm.hd.p[k] * wm1[k * 128 + t];
        sm.hd.h[t] = fmaxf(a, 0.f);
    }
    __syncthreads();
    if (t < 128) {
        float acc[4];
#pragma unroll
        for (int j = 0; j < 4; ++j) acc[j] = bm2[j * 128 + t];
        for (int k = 0; k < 128; ++k) {
            float hv = sm.hd.h[k];
#pragma unroll
            for (int j = 0; j < 4; ++j) acc[j] += hv * wm2[k * 512 + j * 128 + t];
        }
#pragma unroll
        for (int j = 0; j < 4; ++j) out[(size_t)g * 512 + j * 128 + t] = acc[j];
    }
}

extern "C" void kernel_launch(void* const* d_in, const int* in_sizes, int n_in,
                              void* d_out, int out_size, void* d_ws, size_t ws_size,
                              hipStream_t stream) {
    const float* x = (const float*)d_in[0];
    const int* ei = (const int*)d_in[1];
    const int* batch = (const int*)d_in[2];
    const float* w1_1 = (const float*)d_in[3];
    const float* b1_1 = (const float*)d_in[4];
    const float* w1_2 = (const float*)d_in[5];
    const float* b1_2 = (const float*)d_in[6];
    const float* w2_1 = (const float*)d_in[7];
    const float* b2_1 = (const float*)d_in[8];
    const float* w2_2 = (const float*)d_in[9];
    const float* b2_2 = (const float*)d_in[10];
    const float* wm1 = (const float*)d_in[11];
    const float* bm1 = (const float*)d_in[12];
    const float* wm2 = (const float*)d_in[13];
    const float* bm2 = (const float*)d_in[14];

    const int E = in_sizes[1] / 2;
    const int M = in_sizes[0] / 128;
    const int* srcp = ei;
    const int* dstp = ei + E;

    char* ws = (char*)d_ws;
    size_t off = 0;
    auto alloc = [&](size_t bytes) -> void* {
        void* ptr = ws + off;
        off += (bytes + 255) & ~(size_t)255;
        return ptr;
    };
    ushort* AB1 = (ushort*)alloc((size_t)M * 256 * 2);
    ushort* AB2 = (ushort*)alloc((size_t)M * 256 * 2);
    ushort* Hagg = (ushort*)alloc((size_t)M * 128 * 2);
    int* rp = (int*)alloc((size_t)(M + 1) * 4);
    int* cursor = (int*)alloc((size_t)M * 4);   // deg during hist, bump cursor during fill
    int* col = (int*)alloc((size_t)E * 4);
    int* gs = (int*)alloc((GRAPHS + 1) * 4);
    float* psum = (float*)alloc(GRAPHS * 128 * 4);
    ushort* wt1a = (ushort*)alloc(256 * 128 * 2);
    ushort* wt1b = (ushort*)alloc(256 * 128 * 2);
    ushort* wt2a = (ushort*)alloc(128 * 128 * 2);
    ushort* wt2b = (ushort*)alloc(128 * 128 * 2);
    float* b256_1 = (float*)alloc(256 * 4);
    float* b256_2 = (float*)alloc(256 * 4);

    const int nbDeg = (M + 255) / 256;
    const int HB = 512;

    // 1. setup
    setup_k<<<128 + 64 + nbDeg + 32 + 2, 256, 0, stream>>>(
        w1_1, w2_1, w1_2, w2_2, b1_1, b2_1, wt1a, wt1b, wt2a, wt2b, b256_1, b256_2,
        cursor, psum, batch, gs, M, nbDeg);
    // 2. hist || layer1 edge-GEMM
    histgemm_k<<<HB + M / 64, 256, 0, stream>>>(dstp, cursor, E, HB, x, wt1a, b256_1, AB1);
    // 3. scan
    scan_k<<<1, 256, 0, stream>>>(cursor, rp, cursor, M);
    // 4. fill
    fill_k<<<(E + 255) / 256, 256, 0, stream>>>(srcp, dstp, cursor, col, E);
    // 5. agg layer1
    agg_g<<<(M + 3) / 4, 256, 0, stream>>>(AB1, rp, col, Hagg, M);
    // 6. fused H1-GEMM + layer2 edge-GEMM
    layer_g<<<M / 64, 256, 0, stream>>>(Hagg, wt2a, b1_2, wt1b, b256_2, rp, AB2);
    // 7. agg layer2
    agg_g<<<(M + 3) / 4, 256, 0, stream>>>(AB2, rp, col, Hagg, M);
    // 8. H2-GEMM + fused pool
    h2pool_k<<<M / 64, 256, 0, stream>>>(Hagg, wt2b, b2_2, rp, batch, psum);
    // 9. head
    head_g<<<GRAPHS, 256, 0, stream>>>(psum, gs, wm1, bm1, wm2, bm2, (float*)d_out);
}